// Round 1
// 7164.208 us; speedup vs baseline: 1.1360x; 1.1360x over previous
//
#include <hip/hip_runtime.h>
#include <hip/hip_bf16.h>
#include <stdint.h>

// ---------------------------------------------------------------------------
// DiffusionModel: 100 fused steps of x <- x + B*(x@Wx + t*csum + b) + s*noise
// R6: 64 rows/block (512 blocks x 1024 thr), double-buffered xs image ->
// ONE barrier/step, packed bf16 converts (v_cvt_pk_bf16_f32, RNE-identical).
// Rationale (rocprof R5): VALUBusy 55 / MfmaUtil 8.6 -> VALU-bound at only
// 55% issue; idle = W-load latency (FETCH 17.4 GB: blob misses L2 ~1/3 of
// 52 GB requests) + 2 barriers/step. 64 rows halves W traffic and doubles
// MFMA-per-load cover; dbuf removes one barrier; cvt_pk cuts ~3.5 ops/elem.
//
// REGISTER MODEL (R2-R5): budget = 512/waves_per_EU; (1024,4) -> 128 total
// (arch+acc, gfx950 unified). Live set: xr 32 + acc 32 + bf/bfn 16 + addr/
// temps ~30 => ~110-120, fits without spills.
// ---------------------------------------------------------------------------

typedef __attribute__((ext_vector_type(8))) short short8;
typedef __attribute__((ext_vector_type(4))) float f32x4;

#define XS_STRIDE 520          // bf16 elems per x-row in LDS (512+8 pad)
#define NSTEP 100

__device__ __forceinline__ uint32_t rotl32(uint32_t x, int r) {
  return (x << r) | (x >> (32 - r));   // -> v_alignbit_b32
}

// Threefry-2x32, 20 rounds, exactly as jax._src.prng.threefry2x32
__device__ __forceinline__ void tf_rounds(uint32_t k0, uint32_t k1, uint32_t k2,
                                          uint32_t& a, uint32_t& b) {
  a += k0; b += k1;
#define TFR(r) { a += b; b = rotl32(b, (r)); b ^= a; }
  TFR(13) TFR(15) TFR(26) TFR(6)   a += k1; b += k2 + 1u;
  TFR(17) TFR(29) TFR(16) TFR(24)  a += k2; b += k0 + 2u;
  TFR(13) TFR(15) TFR(26) TFR(6)   a += k0; b += k1 + 3u;
  TFR(17) TFR(29) TFR(16) TFR(24)  a += k1; b += k2 + 4u;
  TFR(13) TFR(15) TFR(26) TFR(6)   a += k2; b += k0 + 5u;
#undef TFR
}

// bits -> uniform[-0.99999994, 1) -> sqrt(2)*erfinv(u)  (XLA/Giles erfinv).
// Kept bit-identical to the R5 kernel (RNG must match the JAX reference).
__device__ __forceinline__ float gauss_from_bits(uint32_t bits) {
  const float lo = __uint_as_float(0xBF7FFFFFu);   // nextafter(-1,0)
  float f = __uint_as_float((bits >> 9) | 0x3F800000u) - 1.0f;  // [0,1)
  float u = fmaxf(lo, fmaf(f, 2.0f, lo));
  float om = fmaf(u, -u, 1.0f);                    // 1-u^2 > 0
  float L = __log2f(om);                           // w = -ln2 * L
  float p;
  if (__builtin_expect(L > -7.2134752f, 1)) {      // w < 5
    float z = fmaf(-0.69314718f, L, -2.5f);        // w - 2.5
    p =            2.81022636e-08f;
    p = fmaf(p, z, 3.43273939e-07f);
    p = fmaf(p, z, -3.5233877e-06f);
    p = fmaf(p, z, -4.39150654e-06f);
    p = fmaf(p, z, 0.00021858087f);
    p = fmaf(p, z, -0.00125372503f);
    p = fmaf(p, z, -0.00417768164f);
    p = fmaf(p, z, 0.246640727f);
    p = fmaf(p, z, 1.50140941f);
  } else {
    float z = sqrtf(-0.69314718f * L) - 3.0f;
    p =            -0.000200214257f;
    p = fmaf(p, z, 0.000100950558f);
    p = fmaf(p, z, 0.00134934322f);
    p = fmaf(p, z, -0.00367342844f);
    p = fmaf(p, z, 0.00573950773f);
    p = fmaf(p, z, -0.0076224613f);
    p = fmaf(p, z, 0.00943887047f);
    p = fmaf(p, z, 1.00167406f);
    p = fmaf(p, z, 2.83297682f);
  }
  return 1.41421356f * (p * u);   // sqrt(2) * erfinv(u)
}

// f32 -> bf16 RNE (bit trick) — prep kernel only
__device__ __forceinline__ uint16_t f2bf(float f) {
  uint32_t u = __float_as_uint(f);
  u += 0x7FFFu + ((u >> 16) & 1u);
  return (uint16_t)(u >> 16);
}

// packed pair f32x2 -> bf16x2 (v_cvt_pk_bf16_f32; RNE == bit-trick on
// normal values, which is all x ever is here)
__device__ __forceinline__ uint32_t f2bf_pk(float lo, float hi) {
  union { __hip_bfloat162 h; uint32_t u; } cv;
  cv.h = __float22bfloat162_rn(make_float2(lo, hi));
  return cv.u;
}

// --------------------------------------------------------------------------
// Pre-pass 1: Wx (rows 0..511 of W) -> bf16 blob, UNPADDED [c][n][32]:
// chunk c holds k in [32c,32c+32); B-frag for (c,n,q) = 16B at n*64+q*16 B.
// --------------------------------------------------------------------------
__global__ void prep_w_kernel(const float* __restrict__ W, uint16_t* __restrict__ blob) {
  int id = blockIdx.x * 256 + threadIdx.x;
  if (id >= 512 * 512) return;
  int k = id >> 9;        // feature (K) index
  int n = id & 511;       // output col
  float v = W[k * 512 + n];
  int c = k >> 5, kk = k & 31;
  blob[c * 16384 + n * 32 + kk] = f2bf(v);
}

// Pre-pass 2: csum[n] = sum_j W[512+j][n]  (rank-1 t-embedding part)
__global__ void prep_csum_kernel(const float* __restrict__ W, float* __restrict__ csum) {
  int n = blockIdx.x * 256 + threadIdx.x;
  if (n >= 512) return;
  float s = 0.0f;
  for (int j = 0; j < 512; ++j) s += W[(512 + j) * 512 + n];
  csum[n] = s;
}

// --------------------------------------------------------------------------
// Main fused kernel. MFMA 16x16x32 bf16: A[m=lane&15][k=q*8+j] (from xs),
// B[k][n=lane&15] (direct global 16B coalesced load), C row=4q+reg.
// Block owns rows [64b, 64b+64): mt in 0..3 (16-row tiles); wave w covers
// cols [32w,32w+32): nt in {0,1}. xs double-buffered -> 1 barrier/step.
// --------------------------------------------------------------------------
__global__ __launch_bounds__(1024, 4) void diffuse_kernel(
    const float* __restrict__ x0, const uint16_t* __restrict__ wblob,
    const float* __restrict__ csum, const float* __restrict__ bvec,
    float* __restrict__ out) {
  __shared__ alignas(16) uint16_t xs[2][64 * XS_STRIDE];  // 2 x 66560 B
  __shared__ alignas(8) float2 cb[512];                   // 4096 B {csum, bias}

  const int tid = threadIdx.x;
  const int l15 = tid & 15;
  const int q   = (tid >> 4) & 3;
  const int wv  = tid >> 6;        // wave 0..15
  const int blk = blockIdx.x;      // 0..511

  if (tid < 512) cb[tid] = make_float2(csum[tid], bvec[tid]);

  int ncol[2];
#pragma unroll
  for (int nt = 0; nt < 2; ++nt)
    ncol[nt] = wv * 32 + nt * 16 + l15;

  // fp32 master of x, C-layout: (mt,nt)[j] = local row 16mt+4q+j, col ncol[nt]
  f32x4 xr[4][2];
#pragma unroll
  for (int mt = 0; mt < 4; ++mt)
#pragma unroll
    for (int j = 0; j < 4; ++j) {
      int gr = blk * 64 + mt * 16 + q * 4 + j;
#pragma unroll
      for (int nt = 0; nt < 2; ++nt)
        xr[mt][nt][j] = x0[gr * 512 + ncol[nt]];
    }

  // initial bf16 image into buffer 0 (packed pairs: rows m, m+1)
#pragma unroll
  for (int mt = 0; mt < 4; ++mt)
#pragma unroll
    for (int nt = 0; nt < 2; ++nt)
#pragma unroll
      for (int jj = 0; jj < 2; ++jj) {
        int m = mt * 16 + q * 4 + jj * 2;
        uint32_t pk = f2bf_pk(xr[mt][nt][jj * 2], xr[mt][nt][jj * 2 + 1]);
        xs[0][m * XS_STRIDE + ncol[nt]] = (uint16_t)pk;
        xs[0][(m + 1) * XS_STRIDE + ncol[nt]] = (uint16_t)(pk >> 16);
      }

  const float sq2b = sqrtf(0.02f);   // sqrt(2*beta)
  const f32x4 vzero = {0.0f, 0.0f, 0.0f, 0.0f};

  // Hoisted W bases + chunk-0 prefetch (the c=15 wrap prefetch re-fills
  // chunk 0 for the next step, so this load runs once for the whole kernel).
  const uint16_t* wb0 = wblob + ncol[0] * 32 + q * 8;
  const uint16_t* wb1 = wblob + ncol[1] * 32 + q * 8;
  short8 bf[2], bfn[2];
  bf[0] = *(const short8*)wb0;
  bf[1] = *(const short8*)wb1;

  __syncthreads();   // init image + cb visible to all waves

  for (int t = 0; t < NSTEP; ++t) {
    const uint16_t* xsc = xs[t & 1];
    uint16_t* xsn = xs[(t + 1) & 1];

    // key_t = fold_in(key(42), t) = threefry((0,42),(0,t))  [uniform -> SALU]
    uint32_t kt0 = 0u, kt1 = (uint32_t)t;
    tf_rounds(0u, 42u, 42u ^ 0x1BD11BDAu, kt0, kt1);
    const uint32_t kk2 = kt0 ^ kt1 ^ 0x1BD11BDAu;

    f32x4 acc[4][2];
#pragma unroll
    for (int mt = 0; mt < 4; ++mt)
#pragma unroll
      for (int nt = 0; nt < 2; ++nt)
        acc[mt][nt] = vzero;

    // ---- K-loop: no barriers; B prefetched one chunk ahead;
    //      8 MFMAs + 4 ds_read_b128 per 2 global loads ----
    for (int c = 0; c < 16; ++c) {
      int cn = (c + 1) & 15;
      bfn[0] = *(const short8*)(wb0 + cn * 16384);
      bfn[1] = *(const short8*)(wb1 + cn * 16384);
#pragma unroll
      for (int mt = 0; mt < 4; ++mt) {
        short8 af = *(const short8*)&xsc[(mt * 16 + l15) * XS_STRIDE + c * 32 + q * 8];
        acc[mt][0] = __builtin_amdgcn_mfma_f32_16x16x32_bf16(af, bf[0], acc[mt][0], 0, 0, 0);
        acc[mt][1] = __builtin_amdgcn_mfma_f32_16x16x32_bf16(af, bf[1], acc[mt][1], 0, 0, 0);
      }
      bf[0] = bfn[0];
      bf[1] = bfn[1];
    }

    // ---- noise + update (VALU only, barrier-free; consumes acc early) ----
    const float tf = (float)t;
    float tc[2];
#pragma unroll
    for (int nt = 0; nt < 2; ++nt) {
      const float2 cbv = cb[ncol[nt]];
      tc[nt] = fmaf(tf, cbv.x, cbv.y);
    }
#pragma unroll
    for (int mt = 0; mt < 4; ++mt) {
#pragma unroll
      for (int nt = 0; nt < 2; ++nt) {
        const uint32_t ebase =
            (uint32_t)((blk * 64 + mt * 16 + q * 4) * 512 + ncol[nt]);
#pragma unroll
        for (int j = 0; j < 4; ++j) {
          float sc = acc[mt][nt][j] + tc[nt];
          float xv = fmaf(0.01f, sc, xr[mt][nt][j]);  // x + B*score (ref order)
          uint32_t a = 0u, b = ebase + (uint32_t)(j * 512);
          tf_rounds(kt0, kt1, kk2, a, b);
          float n = gauss_from_bits(a ^ b);
          xv = fmaf(sq2b, n, xv);                     // + s*noise
          xr[mt][nt][j] = xv;
        }
      }
    }

    // ---- write next-step image to the OTHER buffer; single barrier ----
    // (readers of xsc all finished above; writers of xsc at t+2 are fenced
    //  by the barriers at the end of steps t and t+1)
    if (t + 1 < NSTEP) {
#pragma unroll
      for (int mt = 0; mt < 4; ++mt)
#pragma unroll
        for (int nt = 0; nt < 2; ++nt)
#pragma unroll
          for (int jj = 0; jj < 2; ++jj) {
            int m = mt * 16 + q * 4 + jj * 2;
            uint32_t pk = f2bf_pk(xr[mt][nt][jj * 2], xr[mt][nt][jj * 2 + 1]);
            xsn[m * XS_STRIDE + ncol[nt]] = (uint16_t)pk;
            xsn[(m + 1) * XS_STRIDE + ncol[nt]] = (uint16_t)(pk >> 16);
          }
      __syncthreads();
    }
  }

  // final store (fp32)
#pragma unroll
  for (int mt = 0; mt < 4; ++mt)
#pragma unroll
    for (int j = 0; j < 4; ++j) {
      int gr = blk * 64 + mt * 16 + q * 4 + j;
#pragma unroll
      for (int nt = 0; nt < 2; ++nt)
        out[gr * 512 + ncol[nt]] = xr[mt][nt][j];
    }
}

extern "C" void kernel_launch(void* const* d_in, const int* in_sizes, int n_in,
                              void* d_out, int out_size, void* d_ws, size_t ws_size,
                              hipStream_t stream) {
  const float* x0 = (const float*)d_in[0];   // (32768, 512)
  const float* W  = (const float*)d_in[1];   // (1024, 512)
  const float* bv = (const float*)d_in[2];   // (512,)
  float* out = (float*)d_out;

  uint16_t* blob = (uint16_t*)d_ws;                     // 512 KB bf16 W-blob
  float* csum = (float*)((char*)d_ws + 16 * 16384 * 2); // +2 KB

  prep_w_kernel<<<dim3(1024), dim3(256), 0, stream>>>(W, blob);
  prep_csum_kernel<<<dim3(2), dim3(256), 0, stream>>>(W, csum);
  diffuse_kernel<<<dim3(512), dim3(1024), 0, stream>>>(x0, blob, csum, bv, out);
}

// Round 2
// 6565.279 us; speedup vs baseline: 1.2396x; 1.0912x over previous
//
#include <hip/hip_runtime.h>
#include <hip/hip_bf16.h>
#include <stdint.h>

// ---------------------------------------------------------------------------
// DiffusionModel: 100 fused steps of x <- x + B*(x@Wx + t*csum + b) + s*noise
// R7: 64 rows/block kept, but K-loop SPLIT BY nt (column half) to cut peak
// register liveness: acc 32->16, bf/bfn 16->12 => ~90 total, inside the
// (1024,4) budget of 128 -> no scratch spills. R6 post-mortem: WRITE_SIZE
// 0.55->3.56 GB proved xr spilled (64-arch/64-acc split); spill traffic also
// thrashed L2 and kept blob miss rate high. Double-buffered xs still gives
// ONE barrier/step (nt=0's xsn writes overlap nt=1's xsc reads). W prefetch
// is a rolling depth-2 stream ACROSS sweeps (chunk addrs are t-invariant),
// so the VALU-heavy update phase hides each next sweep's first loads.
//
// REGISTER MODEL (R2-R6 measured): __launch_bounds__ 2nd arg = min waves/EU;
// budget (VGPR+AGPR unified) = 512/arg2. (1024,4) -> 128. Exceeding the
// compiler's arch-side split shows up as VGPR_Count=64 + GBs of phantom
// scratch WRITE_SIZE (R6: 3.56 GB). Keep peak live < ~100.
// ---------------------------------------------------------------------------

typedef __attribute__((ext_vector_type(8))) short short8;
typedef __attribute__((ext_vector_type(4))) float f32x4;

#define XS_STRIDE 520          // bf16 elems per x-row in LDS (512+8 pad)
#define NSTEP 100

__device__ __forceinline__ uint32_t rotl32(uint32_t x, int r) {
  return (x << r) | (x >> (32 - r));   // -> v_alignbit_b32
}

// Threefry-2x32, 20 rounds, exactly as jax._src.prng.threefry2x32
__device__ __forceinline__ void tf_rounds(uint32_t k0, uint32_t k1, uint32_t k2,
                                          uint32_t& a, uint32_t& b) {
  a += k0; b += k1;
#define TFR(r) { a += b; b = rotl32(b, (r)); b ^= a; }
  TFR(13) TFR(15) TFR(26) TFR(6)   a += k1; b += k2 + 1u;
  TFR(17) TFR(29) TFR(16) TFR(24)  a += k2; b += k0 + 2u;
  TFR(13) TFR(15) TFR(26) TFR(6)   a += k0; b += k1 + 3u;
  TFR(17) TFR(29) TFR(16) TFR(24)  a += k1; b += k2 + 4u;
  TFR(13) TFR(15) TFR(26) TFR(6)   a += k2; b += k0 + 5u;
#undef TFR
}

// bits -> uniform[-0.99999994, 1) -> sqrt(2)*erfinv(u)  (XLA/Giles erfinv).
// Bit-identical to R5/R6 (RNG must match the JAX reference).
__device__ __forceinline__ float gauss_from_bits(uint32_t bits) {
  const float lo = __uint_as_float(0xBF7FFFFFu);   // nextafter(-1,0)
  float f = __uint_as_float((bits >> 9) | 0x3F800000u) - 1.0f;  // [0,1)
  float u = fmaxf(lo, fmaf(f, 2.0f, lo));
  float om = fmaf(u, -u, 1.0f);                    // 1-u^2 > 0
  float L = __log2f(om);                           // w = -ln2 * L
  float p;
  if (__builtin_expect(L > -7.2134752f, 1)) {      // w < 5
    float z = fmaf(-0.69314718f, L, -2.5f);        // w - 2.5
    p =            2.81022636e-08f;
    p = fmaf(p, z, 3.43273939e-07f);
    p = fmaf(p, z, -3.5233877e-06f);
    p = fmaf(p, z, -4.39150654e-06f);
    p = fmaf(p, z, 0.00021858087f);
    p = fmaf(p, z, -0.00125372503f);
    p = fmaf(p, z, -0.00417768164f);
    p = fmaf(p, z, 0.246640727f);
    p = fmaf(p, z, 1.50140941f);
  } else {
    float z = sqrtf(-0.69314718f * L) - 3.0f;
    p =            -0.000200214257f;
    p = fmaf(p, z, 0.000100950558f);
    p = fmaf(p, z, 0.00134934322f);
    p = fmaf(p, z, -0.00367342844f);
    p = fmaf(p, z, 0.00573950773f);
    p = fmaf(p, z, -0.0076224613f);
    p = fmaf(p, z, 0.00943887047f);
    p = fmaf(p, z, 1.00167406f);
    p = fmaf(p, z, 2.83297682f);
  }
  return 1.41421356f * (p * u);   // sqrt(2) * erfinv(u)
}

// f32 -> bf16 RNE (bit trick) — prep kernel only
__device__ __forceinline__ uint16_t f2bf(float f) {
  uint32_t u = __float_as_uint(f);
  u += 0x7FFFu + ((u >> 16) & 1u);
  return (uint16_t)(u >> 16);
}

// packed pair f32x2 -> bf16x2 (v_cvt_pk_bf16_f32; RNE == bit-trick on
// normal values, which is all x ever is here)
__device__ __forceinline__ uint32_t f2bf_pk(float lo, float hi) {
  union { __hip_bfloat162 h; uint32_t u; } cv;
  cv.h = __float22bfloat162_rn(make_float2(lo, hi));
  return cv.u;
}

// --------------------------------------------------------------------------
// Pre-pass 1: Wx (rows 0..511 of W) -> bf16 blob, UNPADDED [c][n][32]:
// chunk c holds k in [32c,32c+32); B-frag for (c,n,q) = 16B at n*64+q*16 B.
// --------------------------------------------------------------------------
__global__ void prep_w_kernel(const float* __restrict__ W, uint16_t* __restrict__ blob) {
  int id = blockIdx.x * 256 + threadIdx.x;
  if (id >= 512 * 512) return;
  int k = id >> 9;        // feature (K) index
  int n = id & 511;       // output col
  float v = W[k * 512 + n];
  int c = k >> 5, kk = k & 31;
  blob[c * 16384 + n * 32 + kk] = f2bf(v);
}

// Pre-pass 2: csum[n] = sum_j W[512+j][n]  (rank-1 t-embedding part)
__global__ void prep_csum_kernel(const float* __restrict__ W, float* __restrict__ csum) {
  int n = blockIdx.x * 256 + threadIdx.x;
  if (n >= 512) return;
  float s = 0.0f;
  for (int j = 0; j < 512; ++j) s += W[(512 + j) * 512 + n];
  csum[n] = s;
}

// --------------------------------------------------------------------------
// Main fused kernel. MFMA 16x16x32 bf16: A[m=lane&15][k=q*8+j] (from xs),
// B[k][n=lane&15] (direct global 16B coalesced load), C row=4q+reg.
// Block owns rows [64b, 64b+64): mt in 0..3 (16-row tiles); wave w covers
// cols [32w,32w+32): nt in {0,1}, processed as two SEQUENTIAL sweeps.
// xs double-buffered -> 1 barrier/step.
// --------------------------------------------------------------------------
__global__ __launch_bounds__(1024, 4) void diffuse_kernel(
    const float* __restrict__ x0, const uint16_t* __restrict__ wblob,
    const float* __restrict__ csum, const float* __restrict__ bvec,
    float* __restrict__ out) {
  __shared__ alignas(16) uint16_t xs[2][64 * XS_STRIDE];  // 2 x 66560 B
  __shared__ alignas(8) float2 cb[512];                   // 4096 B {csum, bias}

  const int tid = threadIdx.x;
  const int l15 = tid & 15;
  const int q   = (tid >> 4) & 3;
  const int wv  = tid >> 6;        // wave 0..15
  const int blk = blockIdx.x;      // 0..511

  if (tid < 512) cb[tid] = make_float2(csum[tid], bvec[tid]);

  int ncol[2];
#pragma unroll
  for (int nt = 0; nt < 2; ++nt)
    ncol[nt] = wv * 32 + nt * 16 + l15;

  // fp32 master of x, C-layout: (mt,nt)[j] = local row 16mt+4q+j, col ncol[nt]
  f32x4 xr[4][2];
#pragma unroll
  for (int mt = 0; mt < 4; ++mt)
#pragma unroll
    for (int j = 0; j < 4; ++j) {
      int gr = blk * 64 + mt * 16 + q * 4 + j;
#pragma unroll
      for (int nt = 0; nt < 2; ++nt)
        xr[mt][nt][j] = x0[gr * 512 + ncol[nt]];
    }

  // initial bf16 image into buffer 0 (packed pairs: rows m, m+1)
#pragma unroll
  for (int mt = 0; mt < 4; ++mt)
#pragma unroll
    for (int nt = 0; nt < 2; ++nt)
#pragma unroll
      for (int jj = 0; jj < 2; ++jj) {
        int m = mt * 16 + q * 4 + jj * 2;
        uint32_t pk = f2bf_pk(xr[mt][nt][jj * 2], xr[mt][nt][jj * 2 + 1]);
        xs[0][m * XS_STRIDE + ncol[nt]] = (uint16_t)pk;
        xs[0][(m + 1) * XS_STRIDE + ncol[nt]] = (uint16_t)(pk >> 16);
      }

  const float sq2b = sqrtf(0.02f);   // sqrt(2*beta)
  const f32x4 vzero = {0.0f, 0.0f, 0.0f, 0.0f};

  // W fragment bases per column half; chunk addresses are t-invariant, so the
  // prefetch stream is perfectly periodic: nt0 c0..15, nt1 c0..15, nt0 c0..15...
  const uint16_t* wb[2] = {wblob + ncol[0] * 32 + q * 8,
                           wblob + ncol[1] * 32 + q * 8};
  // rolling depth-2 prefetch: bf0/bf1 = chunks 0,1 of the upcoming sweep (nt=0)
  short8 bf0 = *(const short8*)(wb[0]);
  short8 bf1 = *(const short8*)(wb[0] + 16384);

  __syncthreads();   // init image + cb visible to all waves
  const float2 cbv0 = cb[ncol[0]];
  const float2 cbv1 = cb[ncol[1]];

  for (int t = 0; t < NSTEP; ++t) {
    const uint16_t* xsc = xs[t & 1];
    uint16_t* xsn = xs[(t + 1) & 1];

    // key_t = fold_in(key(42), t) = threefry((0,42),(0,t))  [uniform -> SALU]
    uint32_t kt0 = 0u, kt1 = (uint32_t)t;
    tf_rounds(0u, 42u, 42u ^ 0x1BD11BDAu, kt0, kt1);
    const uint32_t kk2 = kt0 ^ kt1 ^ 0x1BD11BDAu;
    const float tf = (float)t;

#pragma unroll
    for (int nt = 0; nt < 2; ++nt) {
      f32x4 acc[4];
#pragma unroll
      for (int mt = 0; mt < 4; ++mt) acc[mt] = vzero;

      // ---- K sweep for this column half: 4 MFMAs + 4 ds_read_b128 per
      //      prefetched 16B W-load; prefetch rolls 2 chunks ahead and wraps
      //      into the NEXT sweep's chunks (update phase hides that latency) --
#pragma unroll
      for (int c = 0; c < 16; ++c) {
        const uint16_t* pp = (c < 14) ? (wb[nt] + (c + 2) * 16384)
                                      : (wb[nt ^ 1] + (c - 14) * 16384);
        short8 bf2 = *(const short8*)pp;
#pragma unroll
        for (int mt = 0; mt < 4; ++mt) {
          short8 af = *(const short8*)&xsc[(mt * 16 + l15) * XS_STRIDE + c * 32 + q * 8];
          acc[mt] = __builtin_amdgcn_mfma_f32_16x16x32_bf16(af, bf0, acc[mt], 0, 0, 0);
        }
        bf0 = bf1;
        bf1 = bf2;
      }

      // ---- noise + update for this half (VALU only, barrier-free) ----
      const float2 cbv = nt ? cbv1 : cbv0;
      const float tc = fmaf(tf, cbv.x, cbv.y);
#pragma unroll
      for (int mt = 0; mt < 4; ++mt) {
        const uint32_t ebase =
            (uint32_t)((blk * 64 + mt * 16 + q * 4) * 512 + ncol[nt]);
#pragma unroll
        for (int j = 0; j < 4; ++j) {
          float sc = acc[mt][j] + tc;
          float xv = fmaf(0.01f, sc, xr[mt][nt][j]);  // x + B*score (ref order)
          uint32_t a = 0u, b = ebase + (uint32_t)(j * 512);
          tf_rounds(kt0, kt1, kk2, a, b);
          float n = gauss_from_bits(a ^ b);
          xr[mt][nt][j] = fmaf(sq2b, n, xv);          // + s*noise
        }
        // write next-step image for this half (other buffer; fenced by the
        // end-of-step barrier below + end-of-previous-step barrier)
        if (t + 1 < NSTEP) {
#pragma unroll
          for (int jj = 0; jj < 2; ++jj) {
            int m = mt * 16 + q * 4 + jj * 2;
            uint32_t pk = f2bf_pk(xr[mt][nt][jj * 2], xr[mt][nt][jj * 2 + 1]);
            xsn[m * XS_STRIDE + ncol[nt]] = (uint16_t)pk;
            xsn[(m + 1) * XS_STRIDE + ncol[nt]] = (uint16_t)(pk >> 16);
          }
        }
      }
    }

    if (t + 1 < NSTEP) __syncthreads();
  }

  // final store (fp32)
#pragma unroll
  for (int mt = 0; mt < 4; ++mt)
#pragma unroll
    for (int j = 0; j < 4; ++j) {
      int gr = blk * 64 + mt * 16 + q * 4 + j;
#pragma unroll
      for (int nt = 0; nt < 2; ++nt)
        out[gr * 512 + ncol[nt]] = xr[mt][nt][j];
    }
}

extern "C" void kernel_launch(void* const* d_in, const int* in_sizes, int n_in,
                              void* d_out, int out_size, void* d_ws, size_t ws_size,
                              hipStream_t stream) {
  const float* x0 = (const float*)d_in[0];   // (32768, 512)
  const float* W  = (const float*)d_in[1];   // (1024, 512)
  const float* bv = (const float*)d_in[2];   // (512,)
  float* out = (float*)d_out;

  uint16_t* blob = (uint16_t*)d_ws;                     // 512 KB bf16 W-blob
  float* csum = (float*)((char*)d_ws + 16 * 16384 * 2); // +2 KB

  prep_w_kernel<<<dim3(1024), dim3(256), 0, stream>>>(W, blob);
  prep_csum_kernel<<<dim3(2), dim3(256), 0, stream>>>(W, csum);
  diffuse_kernel<<<dim3(512), dim3(1024), 0, stream>>>(x0, blob, csum, bv, out);
}